// Round 6
// baseline (2205.684 us; speedup 1.0000x reference)
//
#include <hip/hip_runtime.h>
#include <cstdint>
#include <cstddef>

static constexpr int TT = 1024;   // time steps
static constexpr int BB = 32;     // batch
static constexpr int CC = 256;    // channels (= 2H)
static constexpr int HH = 128;    // hidden per direction
static constexpr int GG = 512;    // 4H gates
static constexpr int MM = TT * BB;

typedef float f32x2 __attribute__((ext_vector_type(2)));

__device__ __forceinline__ float fsig(float x) { return 1.f / (1.f + __expf(-x)); }
__device__ __forceinline__ float ftanh(float x) {
  float e = __expf(2.f * x);
  return 1.f - 2.f / (e + 1.f);
}

// ---------------- x[B][C][T] -> xs[T][B][C] ----------------
__global__ __launch_bounds__(256) void k_transpose_in(const float* __restrict__ x,
                                                      float* __restrict__ xs) {
  __shared__ float tile[32][33];
  const int t0 = blockIdx.x * 32, c0 = blockIdx.y * 32, b = blockIdx.z;
  const int tx = threadIdx.x, ty = threadIdx.y;
#pragma unroll
  for (int i = 0; i < 4; i++) {
    const int cc = ty + i * 8;
    tile[cc][tx] = x[((size_t)b * CC + (c0 + cc)) * TT + t0 + tx];
  }
  __syncthreads();
#pragma unroll
  for (int i = 0; i < 4; i++) {
    const int tt = ty + i * 8;
    xs[((size_t)(t0 + tt) * BB + b) * CC + c0 + tx] = tile[tx][tt];
  }
}

// ---------------- h2[T][B][C] -> out[B][C][T] ----------------
__global__ __launch_bounds__(256) void k_transpose_out(const float* __restrict__ h2,
                                                       float* __restrict__ out) {
  __shared__ float tile[32][33];
  const int t0 = blockIdx.x * 32, c0 = blockIdx.y * 32, b = blockIdx.z;
  const int tx = threadIdx.x, ty = threadIdx.y;
#pragma unroll
  for (int i = 0; i < 4; i++) {
    const int tt = ty + i * 8;
    tile[tt][tx] = h2[((size_t)(t0 + tt) * BB + b) * CC + c0 + tx];
  }
  __syncthreads();
#pragma unroll
  for (int i = 0; i < 4; i++) {
    const int cc = ty + i * 8;
    out[((size_t)b * CC + (c0 + cc)) * TT + t0 + tx] = tile[tx][cc];
  }
}

// ---------------- gx[d][m][g] = X[m][:]·W[d][g][:] + bih[d][g]+bhh[d][g] ----------------
__global__ __launch_bounds__(256) void k_gemm_ih(const float* __restrict__ X,
                                                 const float* __restrict__ W,
                                                 const float* __restrict__ bih,
                                                 const float* __restrict__ bhh,
                                                 float* __restrict__ gx, int M) {
  const int d = blockIdx.z;
  const int row0 = blockIdx.y * 128;
  const int col0 = blockIdx.x * 64;
  const float* Wd = W + (size_t)d * GG * CC;
  __shared__ float As[16][132];  // [k][m], padded
  __shared__ float Ws[16][68];   // [k][n]
  const int tid = threadIdx.x;
  const int tm = tid >> 4;        // 0..15 -> 8 rows each
  const int tn = tid & 15;        // 0..15 -> 4 cols each
  const int lr = tid >> 2;        // 0..63
  const int lk = (tid & 3) * 4;   // 0,4,8,12

  float acc[8][4] = {};
  for (int k0 = 0; k0 < CC; k0 += 16) {
    const float4 a0 = *(const float4*)&X[(size_t)(row0 + lr) * CC + k0 + lk];
    const float4 a1 = *(const float4*)&X[(size_t)(row0 + 64 + lr) * CC + k0 + lk];
    const float4 wv = *(const float4*)&Wd[(size_t)(col0 + lr) * CC + k0 + lk];
    __syncthreads();  // protect LDS from previous iteration's readers
    As[lk + 0][lr] = a0.x; As[lk + 1][lr] = a0.y; As[lk + 2][lr] = a0.z; As[lk + 3][lr] = a0.w;
    As[lk + 0][64 + lr] = a1.x; As[lk + 1][64 + lr] = a1.y; As[lk + 2][64 + lr] = a1.z; As[lk + 3][64 + lr] = a1.w;
    Ws[lk + 0][lr] = wv.x; Ws[lk + 1][lr] = wv.y; Ws[lk + 2][lr] = wv.z; Ws[lk + 3][lr] = wv.w;
    __syncthreads();
#pragma unroll
    for (int kk = 0; kk < 16; kk++) {
      const float4 av0 = *(const float4*)&As[kk][tm * 8];
      const float4 av1 = *(const float4*)&As[kk][tm * 8 + 4];
      const float4 bv = *(const float4*)&Ws[kk][tn * 4];
      const float a[8] = {av0.x, av0.y, av0.z, av0.w, av1.x, av1.y, av1.z, av1.w};
      const float bb4[4] = {bv.x, bv.y, bv.z, bv.w};
#pragma unroll
      for (int i = 0; i < 8; i++)
#pragma unroll
        for (int j = 0; j < 4; j++) acc[i][j] = fmaf(a[i], bb4[j], acc[i][j]);
    }
  }
  float bias[4];
#pragma unroll
  for (int j = 0; j < 4; j++) {
    const int col = col0 + tn * 4 + j;
    bias[j] = bih[d * GG + col] + bhh[d * GG + col];
  }
#pragma unroll
  for (int i = 0; i < 8; i++) {
    const int row = row0 + tm * 8 + i;
    float4 o;
    o.x = acc[i][0] + bias[0];
    o.y = acc[i][1] + bias[1];
    o.z = acc[i][2] + bias[2];
    o.w = acc[i][3] + bias[3];
    *(float4*)&gx[((size_t)d * M + row) * GG + col0 + tn * 4] = o;
  }
}

// ---------------- persistent recurrence: one WG per (d,b) ----------------
// R5 structure (R=4 rows/thread, 82 LDS insts/step) + two residency-forcing changes:
//   1) __launch_bounds__(512,1): VGPR budget 512 (HW still fits 2 waves/SIMD at ~190)
//   2) dot loop = inline-asm v_pk_fma_f32 with "v"-constrained f32x2 weights: every
//      step's use demands arch VGPRs -> allocator must keep all 128 floats resident
//      (R5: VGPR=92 proved the asm-pin alone didn't; weights were L2-streamed or AGPR'd)
__global__ __launch_bounds__(512, 1) void k_lstm_rec(const float* __restrict__ gx,
                                                     const float* __restrict__ Whh,
                                                     float* __restrict__ hout) {
  const int b = blockIdx.x & 31;
  const int d = blockIdx.x >> 5;
  const int tid = threadIdx.x;
  const int q = tid >> 7;       // K-quarter 0..3 (wave-uniform)
  const int j = tid & 127;      // h index 0..127
  __shared__ __align__(16) float h_s[HH];
  __shared__ __align__(16) float part[4][HH][4];  // [q][j][gate]

  // 4 gates x 32 K weights as 64 f32x2 pairs, register-resident
  f32x2 w2[4][16];
  {
    const float* base = Whh + (size_t)d * GG * HH;
#pragma unroll
    for (int gi = 0; gi < 4; gi++) {
      const float4* wrow = (const float4*)(base + (size_t)(gi * HH + j) * HH + q * 32);
#pragma unroll
      for (int k = 0; k < 8; k++) {
        const float4 t4 = wrow[k];
        w2[gi][2 * k]     = f32x2{t4.x, t4.y};
        w2[gi][2 * k + 1] = f32x2{t4.z, t4.w};
      }
    }
  }
#pragma unroll
  for (int gi = 0; gi < 4; gi++) {
    asm volatile("" : "+v"(w2[gi][0]), "+v"(w2[gi][1]), "+v"(w2[gi][2]), "+v"(w2[gi][3]),
                      "+v"(w2[gi][4]), "+v"(w2[gi][5]), "+v"(w2[gi][6]), "+v"(w2[gi][7]));
    asm volatile("" : "+v"(w2[gi][8]), "+v"(w2[gi][9]), "+v"(w2[gi][10]), "+v"(w2[gi][11]),
                      "+v"(w2[gi][12]), "+v"(w2[gi][13]), "+v"(w2[gi][14]), "+v"(w2[gi][15]));
  }

  if (tid < HH) h_s[tid] = 0.f;
  float c = 0.f;

  const float* gxb = gx + ((size_t)d * TT * BB + b) * (size_t)GG;
  const size_t stride = (size_t)BB * GG;
  int t = d ? (TT - 1) : 0;
  const int tdir = d ? -1 : 1;
  const bool is_act = (tid < HH);

  float gxc0 = 0.f, gxc1 = 0.f, gxc2 = 0.f, gxc3 = 0.f;
  if (is_act) {
    const float* g0 = gxb + (size_t)t * stride + j;
    gxc0 = g0[0]; gxc1 = g0[HH]; gxc2 = g0[2 * HH]; gxc3 = g0[3 * HH];
  }
  __syncthreads();

  for (int s = 0; s < TT; s++) {
    // prefetch next step's gx (independent of h)
    float gxn0 = 0.f, gxn1 = 0.f, gxn2 = 0.f, gxn3 = 0.f;
    if (is_act && s + 1 < TT) {
      const float* g0 = gxb + (size_t)(t + tdir) * stride + j;
      gxn0 = g0[0]; gxn1 = g0[HH]; gxn2 = g0[2 * HH]; gxn3 = g0[3 * HH];
    }

    // h K-slice: 8 uniform ds_read_b128 per wave, split into f32x2 halves
    f32x2 hp[16];
    {
      const float4* hq = (const float4*)(h_s + q * 32);
#pragma unroll
      for (int k = 0; k < 8; k++) {
        const float4 hv = hq[k];
        hp[2 * k]     = f32x2{hv.x, hv.y};
        hp[2 * k + 1] = f32x2{hv.z, hv.w};
      }
    }

    // dot: 4 gates x 32 K as 64 v_pk_fma_f32 (8 independent chains)
    f32x2 a0a = {0.f, 0.f}, a0b = {0.f, 0.f}, a1a = {0.f, 0.f}, a1b = {0.f, 0.f};
    f32x2 a2a = {0.f, 0.f}, a2b = {0.f, 0.f}, a3a = {0.f, 0.f}, a3b = {0.f, 0.f};
#pragma unroll
    for (int k = 0; k < 8; k++) {
      asm("v_pk_fma_f32 %0, %8, %16, %0\n\t"
          "v_pk_fma_f32 %1, %9, %17, %1\n\t"
          "v_pk_fma_f32 %2, %10, %16, %2\n\t"
          "v_pk_fma_f32 %3, %11, %17, %3\n\t"
          "v_pk_fma_f32 %4, %12, %16, %4\n\t"
          "v_pk_fma_f32 %5, %13, %17, %5\n\t"
          "v_pk_fma_f32 %6, %14, %16, %6\n\t"
          "v_pk_fma_f32 %7, %15, %17, %7"
          : "+v"(a0a), "+v"(a0b), "+v"(a1a), "+v"(a1b),
            "+v"(a2a), "+v"(a2b), "+v"(a3a), "+v"(a3b)
          : "v"(w2[0][2 * k]), "v"(w2[0][2 * k + 1]),
            "v"(w2[1][2 * k]), "v"(w2[1][2 * k + 1]),
            "v"(w2[2][2 * k]), "v"(w2[2][2 * k + 1]),
            "v"(w2[3][2 * k]), "v"(w2[3][2 * k + 1]),
            "v"(hp[2 * k]), "v"(hp[2 * k + 1]));
    }
    const float A0 = (a0a.x + a0a.y) + (a0b.x + a0b.y);
    const float A1 = (a1a.x + a1a.y) + (a1b.x + a1b.y);
    const float A2 = (a2a.x + a2a.y) + (a2b.x + a2b.y);
    const float A3 = (a3a.x + a3a.y) + (a3b.x + a3b.y);
    *(float4*)&part[q][j][0] = make_float4(A0, A1, A2, A3);
    __syncthreads();

    if (is_act) {
      const float4 p0 = *(const float4*)&part[0][j][0];
      const float4 p1 = *(const float4*)&part[1][j][0];
      const float4 p2 = *(const float4*)&part[2][j][0];
      const float4 p3 = *(const float4*)&part[3][j][0];
      const float i_g = fsig(p0.x + p1.x + p2.x + p3.x + gxc0);
      const float f_g = fsig(p0.y + p1.y + p2.y + p3.y + gxc1);
      const float g_g = ftanh(p0.z + p1.z + p2.z + p3.z + gxc2);
      const float o_g = fsig(p0.w + p1.w + p2.w + p3.w + gxc3);
      c = f_g * c + i_g * g_g;
      const float h = o_g * ftanh(c);
      h_s[j] = h;
      hout[((size_t)t * BB + b) * CC + d * HH + j] = h;
    }
    __syncthreads();
    gxc0 = gxn0; gxc1 = gxn1; gxc2 = gxn2; gxc3 = gxn3;
    t += tdir;
  }
}

extern "C" void kernel_launch(void* const* d_in, const int* in_sizes, int n_in,
                              void* d_out, int out_size, void* d_ws, size_t ws_size,
                              hipStream_t stream) {
  const float* x    = (const float*)d_in[0];
  const float* W_ih = (const float*)d_in[1];  // [2][2][512][256]
  const float* W_hh = (const float*)d_in[2];  // [2][2][512][128]
  const float* b_ih = (const float*)d_in[3];  // [2][2][512]
  const float* b_hh = (const float*)d_in[4];
  float* out = (float*)d_out;

  if (ws_size < (size_t)160 * 1024 * 1024) return;  // need xs(32MiB)+gx(128MiB)

  char* ws = (char*)d_ws;
  float* xs = (float*)ws;                                   // [T][B][C] 32 MiB
  float* gxbuf = (float*)(ws + (size_t)32 * 1024 * 1024);   // [D][M][512] 128 MiB
  float* h1 = out;  // layer-0 hidden staged in d_out (dead before final transpose)
  float* h2 = xs;   // layer-1 hidden reuses xs region (xs dead after layer-0 GEMM)

  const dim3 tb(32, 8);
  const dim3 tg(TT / 32, CC / 32, BB);

  k_transpose_in<<<tg, tb, 0, stream>>>(x, xs);
  k_gemm_ih<<<dim3(GG / 64, MM / 128, 2), 256, 0, stream>>>(xs, W_ih, b_ih, b_hh, gxbuf, MM);
  k_lstm_rec<<<64, 512, 0, stream>>>(gxbuf, W_hh, h1);
  k_gemm_ih<<<dim3(GG / 64, MM / 128, 2), 256, 0, stream>>>(h1, W_ih + 2 * GG * CC,
                                                            b_ih + 2 * GG, b_hh + 2 * GG, gxbuf, MM);
  k_lstm_rec<<<64, 512, 0, stream>>>(gxbuf, W_hh + 2 * GG * HH, h2);
  k_transpose_out<<<tg, tb, 0, stream>>>(h2, out);
}

// Round 7
// 2088.817 us; speedup vs baseline: 1.0559x; 1.0559x over previous
//
#include <hip/hip_runtime.h>
#include <cstdint>
#include <cstddef>

static constexpr int TT = 1024;   // time steps
static constexpr int BB = 32;     // batch
static constexpr int CC = 256;    // channels (= 2H)
static constexpr int HH = 128;    // hidden per direction
static constexpr int GG = 512;    // 4H gates
static constexpr int MM = TT * BB;

__device__ __forceinline__ float fsig(float x) { return 1.f / (1.f + __expf(-x)); }
__device__ __forceinline__ float ftanh(float x) {
  float e = __expf(2.f * x);
  return 1.f - 2.f / (e + 1.f);
}

// ---------------- x[B][C][T] -> xs[T][B][C] ----------------
__global__ __launch_bounds__(256) void k_transpose_in(const float* __restrict__ x,
                                                      float* __restrict__ xs) {
  __shared__ float tile[32][33];
  const int t0 = blockIdx.x * 32, c0 = blockIdx.y * 32, b = blockIdx.z;
  const int tx = threadIdx.x, ty = threadIdx.y;
#pragma unroll
  for (int i = 0; i < 4; i++) {
    const int cc = ty + i * 8;
    tile[cc][tx] = x[((size_t)b * CC + (c0 + cc)) * TT + t0 + tx];
  }
  __syncthreads();
#pragma unroll
  for (int i = 0; i < 4; i++) {
    const int tt = ty + i * 8;
    xs[((size_t)(t0 + tt) * BB + b) * CC + c0 + tx] = tile[tx][tt];
  }
}

// ---------------- h2[T][B][C] -> out[B][C][T] ----------------
__global__ __launch_bounds__(256) void k_transpose_out(const float* __restrict__ h2,
                                                       float* __restrict__ out) {
  __shared__ float tile[32][33];
  const int t0 = blockIdx.x * 32, c0 = blockIdx.y * 32, b = blockIdx.z;
  const int tx = threadIdx.x, ty = threadIdx.y;
#pragma unroll
  for (int i = 0; i < 4; i++) {
    const int tt = ty + i * 8;
    tile[tt][tx] = h2[((size_t)(t0 + tt) * BB + b) * CC + c0 + tx];
  }
  __syncthreads();
#pragma unroll
  for (int i = 0; i < 4; i++) {
    const int cc = ty + i * 8;
    out[((size_t)b * CC + (c0 + cc)) * TT + t0 + tx] = tile[tx][cc];
  }
}

// ---------------- gx[d][m][g] = X[m][:]·W[d][g][:] + bih[d][g]+bhh[d][g] ----------------
__global__ __launch_bounds__(256) void k_gemm_ih(const float* __restrict__ X,
                                                 const float* __restrict__ W,
                                                 const float* __restrict__ bih,
                                                 const float* __restrict__ bhh,
                                                 float* __restrict__ gx, int M) {
  const int d = blockIdx.z;
  const int row0 = blockIdx.y * 128;
  const int col0 = blockIdx.x * 64;
  const float* Wd = W + (size_t)d * GG * CC;
  __shared__ float As[16][132];  // [k][m], padded
  __shared__ float Ws[16][68];   // [k][n]
  const int tid = threadIdx.x;
  const int tm = tid >> 4;        // 0..15 -> 8 rows each
  const int tn = tid & 15;        // 0..15 -> 4 cols each
  const int lr = tid >> 2;        // 0..63
  const int lk = (tid & 3) * 4;   // 0,4,8,12

  float acc[8][4] = {};
  for (int k0 = 0; k0 < CC; k0 += 16) {
    const float4 a0 = *(const float4*)&X[(size_t)(row0 + lr) * CC + k0 + lk];
    const float4 a1 = *(const float4*)&X[(size_t)(row0 + 64 + lr) * CC + k0 + lk];
    const float4 wv = *(const float4*)&Wd[(size_t)(col0 + lr) * CC + k0 + lk];
    __syncthreads();  // protect LDS from previous iteration's readers
    As[lk + 0][lr] = a0.x; As[lk + 1][lr] = a0.y; As[lk + 2][lr] = a0.z; As[lk + 3][lr] = a0.w;
    As[lk + 0][64 + lr] = a1.x; As[lk + 1][64 + lr] = a1.y; As[lk + 2][64 + lr] = a1.z; As[lk + 3][64 + lr] = a1.w;
    Ws[lk + 0][lr] = wv.x; Ws[lk + 1][lr] = wv.y; Ws[lk + 2][lr] = wv.z; Ws[lk + 3][lr] = wv.w;
    __syncthreads();
#pragma unroll
    for (int kk = 0; kk < 16; kk++) {
      const float4 av0 = *(const float4*)&As[kk][tm * 8];
      const float4 av1 = *(const float4*)&As[kk][tm * 8 + 4];
      const float4 bv = *(const float4*)&Ws[kk][tn * 4];
      const float a[8] = {av0.x, av0.y, av0.z, av0.w, av1.x, av1.y, av1.z, av1.w};
      const float bb4[4] = {bv.x, bv.y, bv.z, bv.w};
#pragma unroll
      for (int i = 0; i < 8; i++)
#pragma unroll
        for (int j = 0; j < 4; j++) acc[i][j] = fmaf(a[i], bb4[j], acc[i][j]);
    }
  }
  float bias[4];
#pragma unroll
  for (int j = 0; j < 4; j++) {
    const int col = col0 + tn * 4 + j;
    bias[j] = bih[d * GG + col] + bhh[d * GG + col];
  }
#pragma unroll
  for (int i = 0; i < 8; i++) {
    const int row = row0 + tm * 8 + i;
    float4 o;
    o.x = acc[i][0] + bias[0];
    o.y = acc[i][1] + bias[1];
    o.z = acc[i][2] + bias[2];
    o.w = acc[i][3] + bias[3];
    *(float4*)&gx[((size_t)d * M + row) * GG + col0 + tn * 4] = o;
  }
}

// ---------------- persistent recurrence: one WG per (d,b) ----------------
// R5 structure, but h goes LDS -> 1 ds_read_b32/wave -> 32 v_readlane -> SGPRs.
// Diagnosis R2-R6: uniform ds_read_bN still delivers N bytes x 64 lanes through the
// LDS return path (broadcast doesn't save return BW); R5's 64 b128 reads/step ~940cyc
// was the wall. SGPR-held h makes the dot v_fmac v,s,v (1 sgpr/instr = legal, full rate)
// and cuts dot-phase LDS to 8 instrs/step.
__global__ __launch_bounds__(512, 1) void k_lstm_rec(const float* __restrict__ gx,
                                                     const float* __restrict__ Whh,
                                                     float* __restrict__ hout) {
  const int b = blockIdx.x & 31;
  const int d = blockIdx.x >> 5;
  const int tid = threadIdx.x;
  const int q = tid >> 7;       // K-quarter 0..3 (wave-uniform)
  const int j = tid & 127;      // h index 0..127
  const int lane = tid & 63;
  __shared__ __align__(16) float h_s[HH];
  __shared__ __align__(16) float part[4][HH][4];  // [q][j][gate]

  // 4 gates x 32 K weights, register-resident (AGPR or VGPR both fine: plain-C fma
  // reads either at full rate; R6 showed forcing "v" only adds copies)
  float4 w4[4][8];
  {
    const float* base = Whh + (size_t)d * GG * HH;
#pragma unroll
    for (int gi = 0; gi < 4; gi++) {
      const float4* wrow = (const float4*)(base + (size_t)(gi * HH + j) * HH + q * 32);
#pragma unroll
      for (int k = 0; k < 8; k++) w4[gi][k] = wrow[k];
    }
  }
#pragma unroll
  for (int gi = 0; gi < 4; gi++)
#pragma unroll
    for (int k = 0; k < 8; k++)
      asm volatile("" : "+v"(w4[gi][k].x), "+v"(w4[gi][k].y), "+v"(w4[gi][k].z), "+v"(w4[gi][k].w));

  if (tid < HH) h_s[tid] = 0.f;
  float c = 0.f;

  const float* gxb = gx + ((size_t)d * TT * BB + b) * (size_t)GG;
  const size_t stride = (size_t)BB * GG;
  int t = d ? (TT - 1) : 0;
  const int tdir = d ? -1 : 1;
  const bool is_act = (tid < HH);  // waves 0-1 (wave-uniform branch)

  float gxc0 = 0.f, gxc1 = 0.f, gxc2 = 0.f, gxc3 = 0.f;
  if (is_act) {
    const float* g0 = gxb + (size_t)t * stride + j;
    gxc0 = g0[0]; gxc1 = g0[HH]; gxc2 = g0[2 * HH]; gxc3 = g0[3 * HH];
  }
  __syncthreads();

  for (int s = 0; s < TT; s++) {
    // prefetch next step's gx (independent of h); divergence confined to waves 0-1
    float gxn0 = 0.f, gxn1 = 0.f, gxn2 = 0.f, gxn3 = 0.f;
    if (is_act && s + 1 < TT) {
      const float* g0 = gxb + (size_t)(t + tdir) * stride + j;
      gxn0 = g0[0]; gxn1 = g0[HH]; gxn2 = g0[2 * HH]; gxn3 = g0[3 * HH];
    }

    // h K-slice: ONE ds_read_b32 per wave (lane l -> h[q*32 + l%32], 2-way alias = free),
    // then 32 readlanes put the slice in SGPRs.
    const float hv = h_s[q * 32 + (lane & 31)];
    float hk[32];
#pragma unroll
    for (int i = 0; i < 32; i++)
      hk[i] = __int_as_float(__builtin_amdgcn_readlane(__float_as_int(hv), i));

    // dot: 4 gates x 32 K, v_fmac v,s,v (weights vector-resident, h scalar-resident)
    float a0 = 0.f, a1 = 0.f, a2 = 0.f, a3 = 0.f;
#pragma unroll
    for (int k = 0; k < 8; k++) {
      const float4 w0 = w4[0][k], w1 = w4[1][k], w2_ = w4[2][k], w3 = w4[3][k];
      a0 = fmaf(w0.x, hk[4 * k], a0);     a0 = fmaf(w0.y, hk[4 * k + 1], a0);
      a0 = fmaf(w0.z, hk[4 * k + 2], a0); a0 = fmaf(w0.w, hk[4 * k + 3], a0);
      a1 = fmaf(w1.x, hk[4 * k], a1);     a1 = fmaf(w1.y, hk[4 * k + 1], a1);
      a1 = fmaf(w1.z, hk[4 * k + 2], a1); a1 = fmaf(w1.w, hk[4 * k + 3], a1);
      a2 = fmaf(w2_.x, hk[4 * k], a2);     a2 = fmaf(w2_.y, hk[4 * k + 1], a2);
      a2 = fmaf(w2_.z, hk[4 * k + 2], a2); a2 = fmaf(w2_.w, hk[4 * k + 3], a2);
      a3 = fmaf(w3.x, hk[4 * k], a3);     a3 = fmaf(w3.y, hk[4 * k + 1], a3);
      a3 = fmaf(w3.z, hk[4 * k + 2], a3); a3 = fmaf(w3.w, hk[4 * k + 3], a3);
    }
    *(float4*)&part[q][j][0] = make_float4(a0, a1, a2, a3);
    __syncthreads();

    if (is_act) {
      const float4 p0 = *(const float4*)&part[0][j][0];
      const float4 p1 = *(const float4*)&part[1][j][0];
      const float4 p2 = *(const float4*)&part[2][j][0];
      const float4 p3 = *(const float4*)&part[3][j][0];
      const float i_g = fsig(p0.x + p1.x + p2.x + p3.x + gxc0);
      const float f_g = fsig(p0.y + p1.y + p2.y + p3.y + gxc1);
      const float g_g = ftanh(p0.z + p1.z + p2.z + p3.z + gxc2);
      const float o_g = fsig(p0.w + p1.w + p2.w + p3.w + gxc3);
      c = f_g * c + i_g * g_g;
      const float h = o_g * ftanh(c);
      h_s[j] = h;
      hout[((size_t)t * BB + b) * CC + d * HH + j] = h;
    }
    __syncthreads();
    gxc0 = gxn0; gxc1 = gxn1; gxc2 = gxn2; gxc3 = gxn3;
    t += tdir;
  }
}

extern "C" void kernel_launch(void* const* d_in, const int* in_sizes, int n_in,
                              void* d_out, int out_size, void* d_ws, size_t ws_size,
                              hipStream_t stream) {
  const float* x    = (const float*)d_in[0];
  const float* W_ih = (const float*)d_in[1];  // [2][2][512][256]
  const float* W_hh = (const float*)d_in[2];  // [2][2][512][128]
  const float* b_ih = (const float*)d_in[3];  // [2][2][512]
  const float* b_hh = (const float*)d_in[4];
  float* out = (float*)d_out;

  if (ws_size < (size_t)160 * 1024 * 1024) return;  // need xs(32MiB)+gx(128MiB)

  char* ws = (char*)d_ws;
  float* xs = (float*)ws;                                   // [T][B][C] 32 MiB
  float* gxbuf = (float*)(ws + (size_t)32 * 1024 * 1024);   // [D][M][512] 128 MiB
  float* h1 = out;  // layer-0 hidden staged in d_out (dead before final transpose)
  float* h2 = xs;   // layer-1 hidden reuses xs region (xs dead after layer-0 GEMM)

  const dim3 tb(32, 8);
  const dim3 tg(TT / 32, CC / 32, BB);

  k_transpose_in<<<tg, tb, 0, stream>>>(x, xs);
  k_gemm_ih<<<dim3(GG / 64, MM / 128, 2), 256, 0, stream>>>(xs, W_ih, b_ih, b_hh, gxbuf, MM);
  k_lstm_rec<<<64, 512, 0, stream>>>(gxbuf, W_hh, h1);
  k_gemm_ih<<<dim3(GG / 64, MM / 128, 2), 256, 0, stream>>>(h1, W_ih + 2 * GG * CC,
                                                            b_ih + 2 * GG, b_hh + 2 * GG, gxbuf, MM);
  k_lstm_rec<<<64, 512, 0, stream>>>(gxbuf, W_hh + 2 * GG * HH, h2);
  k_transpose_out<<<tg, tb, 0, stream>>>(h2, out);
}